// Round 5
// baseline (95.830 us; speedup 1.0000x reference)
//
#include <hip/hip_runtime.h>
#include <math.h>

// Exact fusion of: resize(256->1024) -> warp_perspective(affine) -> resize(1024->256).
// Round-5 change: a coalesced pre-pass interleaves channels ([b][c][y][x] ->
// [b][y][x][c] in d_ws) so each 4-col stencil window row is 12 contiguous
// floats covering all 3 channels -- one cache-line footprint instead of three
// plane-separated ones. Weight math identical to round 2/4 (absmax preserved).

typedef float floatx4 __attribute__((ext_vector_type(4)));

__device__ __forceinline__ floatx4 load4(const float* p) {
    floatx4 v;
    __builtin_memcpy(&v, p, sizeof(v));  // 4B-aligned 16B load -> dwordx4
    return v;
}

// ---- pass 1: channel interleave  xi[b][y][x][c] = x[b][c][y][x] ----
__global__ __launch_bounds__(256) void interleave(
    const float* __restrict__ x, float* __restrict__ xi)
{
    int g = blockIdx.x * 256 + threadIdx.x;   // 16*65536 pixels
    int b = g >> 16;
    int p = g & 65535;
    const float* xb = x + b * 3 * 65536 + p;
    float v0 = xb[0];
    float v1 = xb[65536];
    float v2 = xb[131072];
    float* o = xi + (size_t)g * 3;
    o[0] = v0;
    o[1] = v1;
    o[2] = v2;
}

struct Up { int i0; float w; };

// up-resize coord for 1024-res integer index v: u = 0.25*v - 0.375, clipped
// to [0,255]. At the clip boundaries the fractional weight is exactly 0.
__device__ __forceinline__ Up upc(int v) {
    float u = fmaf(0.25f, (float)v, -0.375f);
    u = fminf(fmaxf(u, 0.0f), 255.0f);
    float f = floorf(u);
    Up r; r.i0 = (int)f; r.w = u - f;
    return r;
}

struct Trip { float w0, w1, w2; int base; };

// merged 3-tap weights (outer bilinear x inner up-bilinear) along one axis,
// for a clipped fine coordinate s in [0,1023].
__device__ __forceinline__ Trip merged3(float s) {
    float f = floorf(s);
    float fr = s - f;
    int v0 = (int)f;
    int v1 = min(v0 + 1, 1023);
    Up c0 = upc(v0), c1 = upc(v1);
    float A0 = 1.0f - fr, A1 = fr;
    float b0 = A1 * (1.0f - c1.w), b1 = A1 * c1.w;
    bool d = (c1.i0 != c0.i0);
    Trip t;
    t.w0 = A0 * (1.0f - c0.w) + (d ? 0.0f : b0);
    t.w1 = A0 * c0.w + (d ? b0 : b1);
    t.w2 = d ? b1 : 0.0f;
    t.base = c0.i0;
    return t;
}

__global__ __launch_bounds__(256) void fused_warp(
    const float* __restrict__ xi,
    const float* __restrict__ paramP, const float* __restrict__ paramM,
    const float* __restrict__ gumbel_u, const float* __restrict__ eps,
    const int* __restrict__ idx,
    float* __restrict__ out, int N)
{
    __shared__ float smem[8];

    int b = blockIdx.z;
    int tid = threadIdx.y * 16 + threadIdx.x;

    // ---- per-block inverse-matrix computation (wave 0 only) ----
    if (tid < 64) {
        float dec = 0.f, sMv = 0.f;
        if (tid < 7) {
            int k = tid;
            int id = idx[b];
            float vP = paramP[k * N + id];
            float pP = 1.0f / (1.0f + expf(-vP));
            float l0 = logf(pP);
            float l1 = logf(1.0f - pP);
            float u0 = gumbel_u[(k * 16 + b) * 2 + 0];
            float u1 = gumbel_u[(k * 16 + b) * 2 + 1];
            float g0 = -logf(-logf(u0));
            float g1 = -logf(-logf(u1));
            dec = (l0 + g0 >= l1 + g1) ? 1.0f : 0.0f;  // argmax tie -> index 0
            float vM = paramM[k * N + id];
            float sig = 1.0f / (1.0f + expf(-vM));
            sMv = sig * eps[k * 16 + b];
        }
        float sP[7], sM[7];
#pragma unroll
        for (int k = 0; k < 7; ++k) {
            sP[k] = __shfl(dec, k, 64);
            sM[k] = __shfl(sMv, k, 64);
        }
        if (tid == 0) {
            float ang = sP[0] * sM[0] * 30.0f;
            float rad = ang * 0.017453292519943295f;
            float ca = cosf(rad), sa = sinf(rad);
            float sx = 1.0f + sP[5] * sM[5] * 0.5f;
            float sy = 1.0f + sP[6] * sM[6] * 0.5f;
            float sr00 = ca * sx, sr01 = sa * sy;
            float sr10 = -sa * sx, sr11 = ca * sy;
            float t0 = 128.0f - (sr00 + sr01) * 128.0f;
            float t1 = 128.0f - (sr10 + sr11) * 128.0f;
            float tx = 256.0f * sP[1] * sM[1] * 0.45f;
            float ty = 256.0f * sP[2] * sM[2] * 0.45f;
            float sh01 = sP[3] * sM[3] * 0.3f;
            float sh10 = sP[4] * sM[4] * 0.3f;
            float e0 = t0 + tx, e1 = t1 + ty;
            float a  = sr00 + sh01 * sr10;
            float bb = sr01 + sh01 * sr11;
            float txm = e0 + sh01 * e1;
            float c  = sh10 * sr00 + sr10;
            float d  = sh10 * sr01 + sr11;
            float tym = sh10 * e0 + e1;
            float det = a * d - bb * c;
            float rdet = 1.0f / det;
            smem[0] = d * rdet;
            smem[1] = -bb * rdet;
            smem[2] = (bb * tym - d * txm) * rdet;
            smem[3] = -c * rdet;
            smem[4] = a * rdet;
            smem[5] = (c * txm - a * tym) * rdet;
        }
    }
    __syncthreads();

    float m00 = smem[0], m01 = smem[1], m02 = smem[2];
    float m10 = smem[3], m11 = smem[4], m12 = smem[5];

    int j = blockIdx.x * 16 + threadIdx.x;
    int i = blockIdx.y * 16 + threadIdx.y;
    const float* xb = xi + (size_t)b * 3 * 65536;   // interleaved plane
    float acc[3] = {0.f, 0.f, 0.f};

#pragma unroll
    for (int p = 0; p < 2; ++p) {
        // sample A: X = 4j+1, sample B: X = 4j+2, shared Y = 4i+1+p
        float XA = (float)(4 * j + 1);
        float Yp = (float)(4 * i + 1 + p);
        float xAu = fmaf(m00, XA, fmaf(m01, Yp, m02));
        float yAu = fmaf(m10, XA, fmaf(m11, Yp, m12));
        float xBu = xAu + m00;
        float yBu = yAu + m10;
        float xsA = fminf(fmaxf(xAu, 0.f), 1023.f);
        float ysA = fminf(fmaxf(yAu, 0.f), 1023.f);
        float xsB = fminf(fmaxf(xBu, 0.f), 1023.f);
        float ysB = fminf(fmaxf(yBu, 0.f), 1023.f);
        Trip cA = merged3(xsA), cB = merged3(xsB);
        Trip rA = merged3(ysA), rB = merged3(ysB);
        int cb = min(cA.base, cB.base);
        int rb = min(rA.base, rB.base);
        float CA[4], CB[4], RA[4], RB[4];
        bool sa_ = (cA.base != cb);
        CA[0] = sa_ ? 0.f : cA.w0;
        CA[1] = sa_ ? cA.w0 : cA.w1;
        CA[2] = sa_ ? cA.w1 : cA.w2;
        CA[3] = sa_ ? cA.w2 : 0.f;
        bool sb_ = (cB.base != cb);
        CB[0] = sb_ ? 0.f : cB.w0;
        CB[1] = sb_ ? cB.w0 : cB.w1;
        CB[2] = sb_ ? cB.w1 : cB.w2;
        CB[3] = sb_ ? cB.w2 : 0.f;
        bool ra_ = (rA.base != rb);
        RA[0] = ra_ ? 0.f : rA.w0;
        RA[1] = ra_ ? rA.w0 : rA.w1;
        RA[2] = ra_ ? rA.w1 : rA.w2;
        RA[3] = ra_ ? rA.w2 : 0.f;
        bool rb_ = (rB.base != rb);
        RB[0] = rb_ ? 0.f : rB.w0;
        RB[1] = rb_ ? rB.w0 : rB.w1;
        RB[2] = rb_ ? rB.w1 : rB.w2;
        RB[3] = rb_ ? rB.w2 : 0.f;

        float W[4][4];
#pragma unroll
        for (int r = 0; r < 4; ++r)
#pragma unroll
            for (int c = 0; c < 4; ++c)
                W[r][c] = fmaf(RB[r], CB[c], RA[r] * CA[c]);

        // right-edge safety: clamp window base to 252; weights for columns
        // > 255 are exactly zero, so rotating right is exact. shift <= 3.
        int base = cb;
        if (cb > 252) {
            int shift = cb - 252;
            base = 252;
            for (int s = 0; s < shift; ++s) {
#pragma unroll
                for (int r = 0; r < 4; ++r) {
                    W[r][3] = W[r][2];
                    W[r][2] = W[r][1];
                    W[r][1] = W[r][0];
                    W[r][0] = 0.f;
                }
            }
        }

        int e0 = rb * 256 + base;                 // rb in [0,255]
        int e1 = min(rb + 1, 255) * 256 + base;   // rows past 255 carry zero
        int e2 = min(rb + 2, 255) * 256 + base;   //   weight; aliasing row 255
        int e3 = min(rb + 3, 255) * 256 + base;   //   is harmless
        int q[4] = {e0 * 3, e1 * 3, e2 * 3, e3 * 3};

        // 4 window rows x 12 contiguous floats (cols x channels interleaved)
#pragma unroll
        for (int r = 0; r < 4; ++r) {
            const float* pr = xb + q[r];
            floatx4 v0 = load4(pr);
            floatx4 v1 = load4(pr + 4);
            floatx4 v2 = load4(pr + 8);
            // channel ch uses elements {3c+ch}, c=0..3
            acc[0] += fmaf(W[r][3], v2.y, fmaf(W[r][2], v1.z, fmaf(W[r][1], v0.w, W[r][0] * v0.x)));
            acc[1] += fmaf(W[r][3], v2.z, fmaf(W[r][2], v1.w, fmaf(W[r][1], v1.x, W[r][0] * v0.y)));
            acc[2] += fmaf(W[r][3], v2.w, fmaf(W[r][2], v2.x, fmaf(W[r][1], v1.y, W[r][0] * v0.z)));
        }
    }

    int obase = ((b * 3) * 256 + i) * 256 + j;
    out[obase]          = 0.25f * acc[0];
    out[obase + 65536]  = 0.25f * acc[1];
    out[obase + 131072] = 0.25f * acc[2];
}

extern "C" void kernel_launch(void* const* d_in, const int* in_sizes, int n_in,
                              void* d_out, int out_size, void* d_ws, size_t ws_size,
                              hipStream_t stream) {
    const float* x      = (const float*)d_in[0];
    const float* paramP = (const float*)d_in[1];
    const float* paramM = (const float*)d_in[2];
    const float* gumbel = (const float*)d_in[3];
    const float* eps    = (const float*)d_in[4];
    const int*   idx    = (const int*)d_in[5];
    float* out = (float*)d_out;
    float* xi  = (float*)d_ws;   // 16*3*65536 floats = 12.6 MB < ws_size
    int N = in_sizes[1] / 7;

    hipLaunchKernelGGL(interleave, dim3(4096), dim3(256), 0, stream, x, xi);
    hipLaunchKernelGGL(fused_warp, dim3(16, 16, 16), dim3(16, 16, 1), 0, stream,
                       xi, paramP, paramM, gumbel, eps, idx, out, N);
}